// Round 4
// baseline (559.177 us; speedup 1.0000x reference)
//
#include <hip/hip_runtime.h>
#include <hip/hip_bf16.h>
#include <math.h>

#define S 4096
#define H 32
#define D 128
#define QLR 1536
#define HID 2048
#define TOPK_N 2048
#define NEGF (-1e30f)
#define KW_N 160

typedef __attribute__((ext_vector_type(8))) short bf16x8;
typedef __attribute__((ext_vector_type(4))) float f32x4;

__device__ __forceinline__ void async_copy16(const void* g, void* l) {
    __builtin_amdgcn_global_load_lds(
        (const __attribute__((address_space(1))) unsigned int*)g,
        (__attribute__((address_space(3))) unsigned int*)l,
        16, 0, 0);
}

__device__ __forceinline__ unsigned short bf16bits(float f) {
    __hip_bfloat16 h = __float2bfloat16(f);
    return *(unsigned short*)&h;
}

__device__ __forceinline__ float bits2f(unsigned short u) {
    unsigned v = ((unsigned)u) << 16;
    return __uint_as_float(v);
}

// ---------------------------------------------------------------------------
// Cast f32 -> bf16 (elementwise, float4 granular)
// ---------------------------------------------------------------------------
__global__ __launch_bounds__(256) void cast_bf16_kernel(
    const float* __restrict__ in, __hip_bfloat16* __restrict__ out, int n4)
{
    int i = blockIdx.x * blockDim.x + threadIdx.x;
    if (i < n4) {
        float4 v = ((const float4*)in)[i];
        ushort4 pack;
        pack.x = bf16bits(v.x);
        pack.y = bf16bits(v.y);
        pack.z = bf16bits(v.z);
        pack.w = bf16bits(v.w);
        *(ushort4*)(out + (size_t)i * 4) = pack;
    }
}

__global__ __launch_bounds__(256) void zero_f32(float* __restrict__ p, int n)
{
    int i = blockIdx.x * blockDim.x + threadIdx.x;
    if (i < n) p[i] = 0.0f;
}

// ---------------------------------------------------------------------------
// Transpose + cast: Wq (1536 x 4096 f32) -> WqT (4096 x 1536 bf16)
// ---------------------------------------------------------------------------
__global__ __launch_bounds__(256) void transpose_cast_kernel(
    const float* __restrict__ in, __hip_bfloat16* __restrict__ out)
{
    __shared__ float sm[32][33];
    const int nb = blockIdx.x;
    const int kb = blockIdx.y;
    const int t = threadIdx.x;
    const int j = t & 31, i0 = t >> 5;
#pragma unroll
    for (int u = 0; u < 4; ++u) {
        int i = i0 + u * 8;
        sm[i][j] = in[(size_t)(kb * 32 + i) * 4096 + nb * 32 + j];
    }
    __syncthreads();
#pragma unroll
    for (int u = 0; u < 4; ++u) {
        int i = i0 + u * 8;
        out[(size_t)(nb * 32 + i) * 1536 + kb * 32 + j] = __float2bfloat16(sm[j][i]);
    }
}

// ---------------------------------------------------------------------------
// Build WkpT (160 x 2048 bf16): rows 0..127 = Wk^T, rows 128..159 = (Wp/64)^T
// ---------------------------------------------------------------------------
__global__ __launch_bounds__(256) void build_wkpT(
    const float* __restrict__ Wk, const float* __restrict__ Wp,
    __hip_bfloat16* __restrict__ WkpT)
{
    int g = blockIdx.x * blockDim.x + threadIdx.x;
    if (g >= KW_N * HID) return;
    int n = g / HID, k = g % HID;
    float v = (n < 128) ? Wk[(size_t)k * 128 + n]
                        : Wp[(size_t)k * 32 + (n - 128)] * 0.015625f;
    WkpT[g] = __float2bfloat16(v);
}

// ---------------------------------------------------------------------------
// Fused k/w projection, split-K=4 MFMA (atomicAdd f32 partials).
// ---------------------------------------------------------------------------
__device__ __forceinline__ void kw_stage(
    const short* __restrict__ hb, const short* __restrict__ WkpT,
    int mt, int koff, int rhi, int e, int wave, short* bufA, short* bufB)
{
#pragma unroll
    for (int it = 0; it < 4; ++it) {
        int r = it * 16 + rhi;
        async_copy16(hb + (size_t)(mt * 64 + r) * HID + koff + e * 8,
                     (void*)(bufA + it * 2048 + wave * 512));
    }
#pragma unroll
    for (int it = 0; it < 10; ++it) {
        int r = it * 16 + rhi;
        async_copy16(WkpT + (size_t)r * HID + koff + e * 8,
                     (void*)(bufB + it * 2048 + wave * 512));
    }
}

__global__ __launch_bounds__(256) void kw_mfma(
    const short* __restrict__ hb,
    const short* __restrict__ WkpT,
    float* __restrict__ kf32,
    float* __restrict__ wbuf)
{
    const int mt = blockIdx.x;
    const int kbase = blockIdx.y * 512;      // split-K = 4, 512 K per block
    const int tid = threadIdx.x;
    const int wave = tid >> 6, lane = tid & 63, grp = lane >> 4, lm = lane & 15;
    __shared__ short As[2][64 * 128];        // 2 x 16KB
    __shared__ short Bs[2][KW_N * 128];      // 2 x 40KB

    const int rhi = tid >> 4;
    const int e = (tid & 15) ^ rhi;

    kw_stage(hb, WkpT, mt, kbase, rhi, e, wave, As[0], Bs[0]);

    f32x4 acc[10] = {};
    int cur = 0;
    for (int kc = 0; kc < 4; ++kc) {
        __syncthreads();
        if (kc < 3)
            kw_stage(hb, WkpT, mt, kbase + (kc + 1) * 128, rhi, e, wave,
                     As[cur ^ 1], Bs[cur ^ 1]);
#pragma unroll
        for (int k4 = 0; k4 < 4; ++k4) {
            int ch = ((k4 << 2) + grp) ^ lm;
            bf16x8 a = *(const bf16x8*)(As[cur] + (wave * 16 + lm) * 128 + ch * 8);
#pragma unroll
            for (int n = 0; n < 10; ++n) {
                bf16x8 b = *(const bf16x8*)(Bs[cur] + (n * 16 + lm) * 128 + ch * 8);
                acc[n] = __builtin_amdgcn_mfma_f32_16x16x32_bf16(a, b, acc[n], 0, 0, 0);
            }
        }
        cur ^= 1;
    }

#pragma unroll
    for (int n = 0; n < 10; ++n) {
#pragma unroll
        for (int r = 0; r < 4; ++r) {
            int row = mt * 64 + wave * 16 + grp * 4 + r;
            int col = n * 16 + lm;
            if (n < 8) atomicAdd(&kf32[(size_t)row * 128 + col], acc[n][r]);
            else       atomicAdd(&wbuf[(size_t)row * 32 + (col - 128)], acc[n][r]);
        }
    }
}

// ---------------------------------------------------------------------------
// bf16 MFMA GEMM, B^T layout (q projection).
// BK=64, double-buffered, XOR-swizzled LDS chunk layout (conflict-free
// ds_read_b128: 8 distinct 16B slots per 16-lane group -> 2-way max).
// 24 K-steps, 1 barrier each, 32 MFMA per barrier.
// ---------------------------------------------------------------------------
__device__ __forceinline__ void gemm_stage64(
    const short* __restrict__ Ag, const short* __restrict__ Bg,
    int row0, int col0, int K, int kc, int tid, short* as, short* bs)
{
    const int w = tid >> 6, lane = tid & 63;
    const int rsub = lane >> 3;               // row within 8-row group
    const int c = (lane & 7) ^ rsub;          // swizzled source chunk
#pragma unroll
    for (int i = 0; i < 4; ++i) {
        int r = w * 32 + i * 8 + rsub;
        async_copy16(Ag + (size_t)(row0 + r) * K + kc + c * 8,
                     (void*)(as + (w * 32 + i * 8) * 64));
        async_copy16(Bg + (size_t)(col0 + r) * K + kc + c * 8,
                     (void*)(bs + (w * 32 + i * 8) * 64));
    }
}

__global__ __launch_bounds__(256, 2) void gemm_bf16_bt(
    const __hip_bfloat16* __restrict__ A, const __hip_bfloat16* __restrict__ BT,
    __hip_bfloat16* __restrict__ C, int M, int N, int K)
{
    __shared__ short As[2][128 * 64];   // 2 x 16KB
    __shared__ short Bs[2][128 * 64];   // 2 x 16KB
    const int tid = threadIdx.x;
    const int wave = tid >> 6, lane = tid & 63, grp = lane >> 4, lm = lane & 15;
    const int row0 = blockIdx.y * 128, col0 = blockIdx.x * 128;
    const short* Ag = (const short*)A;
    const short* Bg = (const short*)BT;

    f32x4 acc[2][8] = {};

    gemm_stage64(Ag, Bg, row0, col0, K, 0, tid, As[0], Bs[0]);
    int cur = 0;
    for (int kc = 0; kc < K; kc += 64) {
        __syncthreads();                 // buf[cur] ready; buf[cur^1] reads done
        if (kc + 64 < K)
            gemm_stage64(Ag, Bg, row0, col0, K, kc + 64, tid,
                         As[cur ^ 1], Bs[cur ^ 1]);
#pragma unroll
        for (int k2 = 0; k2 < 2; ++k2) {
            int pos = ((k2 << 2) + grp) ^ (lm & 7);
            bf16x8 a0 = *(const bf16x8*)(As[cur] + (wave * 32 + lm) * 64 + pos * 8);
            bf16x8 a1 = *(const bf16x8*)(As[cur] + (wave * 32 + 16 + lm) * 64 + pos * 8);
#pragma unroll
            for (int c = 0; c < 8; ++c) {
                bf16x8 b = *(const bf16x8*)(Bs[cur] + (c * 16 + lm) * 64 + pos * 8);
                acc[0][c] = __builtin_amdgcn_mfma_f32_16x16x32_bf16(a0, b, acc[0][c], 0, 0, 0);
                acc[1][c] = __builtin_amdgcn_mfma_f32_16x16x32_bf16(a1, b, acc[1][c], 0, 0, 0);
            }
        }
        cur ^= 1;
    }
#pragma unroll
    for (int t = 0; t < 2; ++t)
#pragma unroll
        for (int c = 0; c < 8; ++c)
#pragma unroll
            for (int r = 0; r < 4; ++r) {
                int rr = row0 + wave * 32 + t * 16 + grp * 4 + r;
                int cc = col0 + c * 16 + lm;
                C[(size_t)rr * N + cc] = __float2bfloat16(acc[t][c][r]);
            }
}

// ---------------------------------------------------------------------------
// RoPE cos/sin table (f32 path; ref is f32 throughout)
// ---------------------------------------------------------------------------
__global__ void sincos_table_kernel(const int* __restrict__ positions,
                                    float* __restrict__ cosT, float* __restrict__ sinT)
{
    int g = blockIdx.x * blockDim.x + threadIdx.x;
    if (g >= S * 32) return;
    int s = g >> 5;
    int p = g & 31;
    // inv = 10000^(-2p/64) = exp2(-log2(10000) * 2p/64)
    float inv = exp2f(-13.28771237954945f * (float)(2 * p) * (1.0f / 64.0f));
    float ang = (float)positions[s] * inv;
    float sv, cv;
    sincosf(ang, &sv, &cv);
    cosT[g] = cv;
    sinT[g] = sv;
}

// ---------------------------------------------------------------------------
// Wave-per-row postprocess: optional LN, RoPE, FWHT. No barriers, no LDS.
// ---------------------------------------------------------------------------
__global__ __launch_bounds__(256) void post_wave(
    const void* __restrict__ in, int in_bf16, __hip_bfloat16* __restrict__ outb,
    const float* __restrict__ cosT, const float* __restrict__ sinT,
    const float* __restrict__ gamma, const float* __restrict__ beta,
    int heads, int do_ln, int nrows)
{
    const int row = blockIdx.x * 4 + (threadIdx.x >> 6);
    if (row >= nrows) return;
    const int l = threadIdx.x & 63;
    const int srow = row / heads;

    float a, b;
    if (in_bf16) {
        unsigned pr = ((const unsigned*)in)[(size_t)row * 64 + l];
        a = bits2f((unsigned short)(pr & 0xffff));
        b = bits2f((unsigned short)(pr >> 16));
    } else {
        float2 v = ((const float2*)in)[(size_t)row * 64 + l];
        a = v.x; b = v.y;
    }

    if (do_ln) {
        float s = a + b;
#pragma unroll
        for (int o = 1; o < 64; o <<= 1) s += __shfl_xor(s, o);
        float mu = s * (1.0f / 128.0f);
        float da = a - mu, db = b - mu;
        float sq = da * da + db * db;
#pragma unroll
        for (int o = 1; o < 64; o <<= 1) sq += __shfl_xor(sq, o);
        float rs = rsqrtf(sq * (1.0f / 128.0f) + 1e-6f);
        float2 g = ((const float2*)gamma)[l];
        float2 bt = ((const float2*)beta)[l];
        a = da * rs * g.x + bt.x;
        b = db * rs * g.y + bt.y;
    }

    if (l < 32) {
        float c = cosT[(size_t)srow * 32 + l];
        float sn = sinT[(size_t)srow * 32 + l];
        float xe = a, xo = b;
        a = xe * c - xo * sn;
        b = xe * sn + xo * c;
    }

    {
        float na = a + b, nb = a - b;
        a = na; b = nb;
    }
#pragma unroll
    for (int m = 1; m < 64; m <<= 1) {
        float pa = __shfl_xor(a, m);
        float pb = __shfl_xor(b, m);
        if (l & m) { a = pa - a; b = pb - b; }
        else       { a = a + pa; b = b + pb; }
    }

    const float sc = 0.08838834764831845f;
    unsigned outp = (unsigned)bf16bits(a * sc) | ((unsigned)bf16bits(b * sc) << 16);
    ((unsigned*)outb)[(size_t)row * 64 + l] = outp;
}

// ---------------------------------------------------------------------------
// MFMA logits v3: barrier-free head loop.
// Block 64x128 (4 waves, wave tile 32x64). k tile staged once to LDS ->
// register-resident bfrag. q A-fragments loaded DIRECTLY global->VGPR
// (64B segments per 4-lane grp quad), double-buffered one head ahead in
// registers. No LDS, no barriers, no global_load_lds in the head loop:
// each wave free-runs; compiler-counted vmcnt waits give a 1-head pipeline.
// ---------------------------------------------------------------------------
__global__ __launch_bounds__(256, 2) void logits_mfma(
    const short* __restrict__ qb,   // S x (H*D) bf16 bits
    const short* __restrict__ kb,   // S x D bf16 bits
    const float* __restrict__ w,    // S x H
    float* __restrict__ out)
{
    const int bx = blockIdx.x;      // 0..31 col tiles (128 wide)
    const int by = blockIdx.y;      // 0..63 row tiles (64 tall)
    const int row0 = by * 64, col0 = bx * 128;
    const int tid = threadIdx.x;

    if (2 * bx > by) {
        const float4 n4 = make_float4(NEGF, NEGF, NEGF, NEGF);
        int c = (tid & 31) * 4;
        for (int r = tid >> 5; r < 64; r += 8)
            *(float4*)&out[(size_t)(row0 + r) * S + col0 + c] = n4;
        return;
    }

    __shared__ short Bs[128 * 128];     // 32KB, one-shot k tile
    __shared__ float Ws[64 * 33];       // w block, padded

    const int wave = tid >> 6, lane = tid & 63, grp = lane >> 4, lm = lane & 15;
    const int wr = wave >> 1, wc = wave & 1;
    const int rhi = tid >> 4;
    const int e = (tid & 15) ^ rhi;

    // stage k tile once
#pragma unroll
    for (int it = 0; it < 8; ++it) {
        int r = it * 16 + rhi;
        async_copy16(kb + (size_t)(col0 + r) * D + e * 8,
                     (void*)(Bs + it * 2048 + wave * 512));
    }
    // stage w block (64 rows x 32 heads) into padded LDS
    for (int i = tid; i < 64 * 32; i += 256) {
        int r = i >> 5, h = i & 31;
        Ws[r * 33 + h] = w[(size_t)row0 * H + i];
    }
    __syncthreads();   // Bs + Ws ready (only barrier in the kernel)

    // cache all k fragments in registers
    bf16x8 bfrag[4][4];
#pragma unroll
    for (int c = 0; c < 4; ++c)
#pragma unroll
        for (int kc = 0; kc < 4; ++kc)
            bfrag[c][kc] = *(const bf16x8*)(
                Bs + (wc * 64 + c * 16 + lm) * 128 + (((kc << 2) + grp) ^ lm) * 8);

    // per-lane q row base pointers (A fragment rows are lane-determined)
    const short* pa0 = qb + (size_t)(row0 + wr * 32 + lm) * (H * D) + grp * 8;
    const short* pa1 = pa0 + (size_t)16 * (H * D);

    f32x4 accP[2][4] = {};
    bf16x8 aA[2][4], aB[2][4];

    auto loadA = [&](bf16x8 (&a)[2][4], int h) {
#pragma unroll
        for (int kc = 0; kc < 4; ++kc) {
            a[0][kc] = *(const bf16x8*)(pa0 + h * 128 + kc * 32);
            a[1][kc] = *(const bf16x8*)(pa1 + h * 128 + kc * 32);
        }
    };
    auto computeH = [&](bf16x8 (&a)[2][4], int h) {
        f32x4 accH[2][4] = {};
        __builtin_amdgcn_s_setprio(1);
#pragma unroll
        for (int kc = 0; kc < 4; ++kc) {
#pragma unroll
            for (int c = 0; c < 4; ++c) {
                accH[0][c] = __builtin_amdgcn_mfma_f32_16x16x32_bf16(a[0][kc], bfrag[c][kc], accH[0][c], 0, 0, 0);
                accH[1][c] = __builtin_amdgcn_mfma_f32_16x16x32_bf16(a[1][kc], bfrag[c][kc], accH[1][c], 0, 0, 0);
            }
        }
        __builtin_amdgcn_s_setprio(0);
#pragma unroll
        for (int t = 0; t < 2; ++t)
#pragma unroll
            for (int r = 0; r < 4; ++r) {
                float wv = Ws[(wr * 32 + t * 16 + grp * 4 + r) * 33 + h];
#pragma unroll
                for (int c = 0; c < 4; ++c)
                    accP[t][c][r] += wv * fmaxf(accH[t][c][r], 0.0f);
            }
    };

    loadA(aA, 0);
    for (int h = 0; h < H; h += 2) {
        loadA(aB, h + 1);          // prefetch odd head
        computeH(aA, h);
        if (h + 2 < H) loadA(aA, h + 2);   // prefetch next even head
        computeH(aB, h + 1);
    }

#pragma unroll
    for (int t = 0; t < 2; ++t)
#pragma unroll
        for (int c = 0; c < 4; ++c)
#pragma unroll
            for (int r = 0; r < 4; ++r) {
                int rr = row0 + wr * 32 + t * 16 + grp * 4 + r;
                int cc = col0 + wc * 64 + c * 16 + lm;
                out[(size_t)rr * S + cc] = (cc <= rr) ? accP[t][c][r] : NEGF;
            }
}

// ---------------------------------------------------------------------------
// Top-k via 4-round radix select (11-bit digits over unique 44-bit keys).
// ---------------------------------------------------------------------------
__device__ __forceinline__ unsigned mono32(float f)
{
    unsigned u = __float_as_uint(f);
    return (u & 0x80000000u) ? ~u : (u | 0x80000000u);
}

__global__ __launch_bounds__(256) void topk_select(
    const float* __restrict__ logits, float* __restrict__ out_idx)
{
    const int row = blockIdx.x;
    const int tid = threadIdx.x;
    const int valid = row + 1;
    float* orow = out_idx + (size_t)row * TOPK_N;

    if (valid <= TOPK_N) {
        for (int p = tid; p < TOPK_N; p += 256)
            orow[p] = (p < valid) ? (float)p : -1.0f;
        return;
    }

    __shared__ float vals[S];
    __shared__ unsigned hist[2048];
    __shared__ unsigned chunk[256];
    __shared__ unsigned long long sh_prefix;
    __shared__ int sh_rem;
    __shared__ unsigned sh_cnt;

    const float* lr = logits + (size_t)row * S;
    for (int j = tid; j < valid; j += 256) vals[j] = lr[j];
    if (tid == 0) { sh_prefix = 0ull; sh_rem = TOPK_N; sh_cnt = 0u; }
    __syncthreads();

    for (int rnd = 0; rnd < 4; ++rnd) {
        const int shift = 33 - 11 * rnd;
        for (int i = tid; i < 2048; i += 256) hist[i] = 0u;
        __syncthreads();
        const unsigned long long pref = sh_prefix;
        const int rem = sh_rem;
        const int hs = shift + 11;
        for (int j = tid; j < valid; j += 256) {
            unsigned long long key = (((unsigned long long)mono32(vals[j])) << 12)
                                   | (unsigned)(4095 - j);
            if ((key >> hs) == (pref >> hs))
                atomicAdd(&hist[(unsigned)(key >> shift) & 2047u], 1u);
        }
        __syncthreads();
        unsigned csum = 0;
#pragma unroll
        for (int d = 0; d < 8; ++d) csum += hist[tid * 8 + d];
        chunk[tid] = csum;
        __syncthreads();
        for (int off = 1; off < 256; off <<= 1) {
            unsigned v = (tid + off < 256) ? chunk[tid + off] : 0u;
            __syncthreads();
            chunk[tid] += v;
            __syncthreads();
        }
        unsigned A = (tid < 255) ? chunk[tid + 1] : 0u;
        for (int dd = 7; dd >= 0; --dd) {
            unsigned c = hist[tid * 8 + dd];
            if (c && A < (unsigned)rem && (unsigned)rem <= A + c) {
                sh_prefix = pref | ((unsigned long long)(tid * 8 + dd) << shift);
                sh_rem = rem - (int)A;
            }
            A += c;
        }
        __syncthreads();
    }

    const unsigned long long Kstar = sh_prefix;
    for (int j = tid; j < valid; j += 256) {
        unsigned long long key = (((unsigned long long)mono32(vals[j])) << 12)
                               | (unsigned)(4095 - j);
        if (key >= Kstar) {
            unsigned p = atomicAdd(&sh_cnt, 1u);
            orow[p] = (float)j;
        }
    }
}

// ---------------------------------------------------------------------------
extern "C" void kernel_launch(void* const* d_in, const int* in_sizes, int n_in,
                              void* d_out, int out_size, void* d_ws, size_t ws_size,
                              hipStream_t stream)
{
    const float* hidden    = (const float*)d_in[0];
    const float* q_lora    = (const float*)d_in[1];
    const int*   positions = (const int*)d_in[2];
    const float* Wq        = (const float*)d_in[3];
    const float* Wk        = (const float*)d_in[4];
    const float* k_gamma   = (const float*)d_in[5];
    const float* k_beta    = (const float*)d_in[6];
    const float* Wp        = (const float*)d_in[7];

    char* ws = (char*)d_ws;
    size_t off = 0;
    __hip_bfloat16* qb16 = (__hip_bfloat16*)(ws + off); off += (size_t)S * H * D * 2;
    __hip_bfloat16* qlb  = (__hip_bfloat16*)(ws + off); off += (size_t)S * QLR * 2;
    __hip_bfloat16* WqT  = (__hip_bfloat16*)(ws + off); off += (size_t)(H * D) * QLR * 2;
    __hip_bfloat16* hb   = (__hip_bfloat16*)(ws + off); off += (size_t)S * HID * 2;
    __hip_bfloat16* WkpT = (__hip_bfloat16*)(ws + off); off += (size_t)KW_N * HID * 2;
    float* kf32 = (float*)(ws + off); off += (size_t)S * D * 4;
    __hip_bfloat16* kb16 = (__hip_bfloat16*)(ws + off); off += (size_t)S * D * 2;
    float* wbuf = (float*)(ws + off); off += (size_t)S * H * 4;
    float* cosT = (float*)(ws + off); off += (size_t)S * 32 * 4;
    float* sinT = (float*)(ws + off); off += (size_t)S * 32 * 4;

    float* out_logits = (float*)d_out;
    float* out_idx = out_logits + (size_t)S * S;

    // 1) casts for the q GEMM
    cast_bf16_kernel<<<(S * QLR / 4 + 255) / 256, 256, 0, stream>>>(q_lora, qlb, S * QLR / 4);
    transpose_cast_kernel<<<dim3((H * D) / 32, QLR / 32), 256, 0, stream>>>(Wq, WqT);

    // 2) q = q_lora @ Wq  (bf16 MFMA, BK=64 dbuf)
    gemm_bf16_bt<<<dim3((H * D) / 128, S / 128), 256, 0, stream>>>(
        qlb, WqT, qb16, S, H * D, QLR);

    // 3) fused k/w projection, split-K=4 MFMA + f32 atomics
    cast_bf16_kernel<<<(S * HID / 4 + 255) / 256, 256, 0, stream>>>(hidden, hb, S * HID / 4);
    build_wkpT<<<(KW_N * HID + 255) / 256, 256, 0, stream>>>(Wk, Wp, WkpT);
    zero_f32<<<(S * D + 255) / 256, 256, 0, stream>>>(kf32, S * D);
    zero_f32<<<(S * H + 255) / 256, 256, 0, stream>>>(wbuf, S * H);
    kw_mfma<<<dim3(S / 64, 4), 256, 0, stream>>>(
        (const short*)hb, (const short*)WkpT, kf32, wbuf);

    // 4) RoPE trig table
    sincos_table_kernel<<<(S * 32) / 256, 256, 0, stream>>>(positions, cosT, sinT);

    // 5) k: LN + RoPE + FWHT -> bf16 ; q: RoPE + FWHT in place (bf16)
    post_wave<<<(S + 3) / 4, 256, 0, stream>>>(
        kf32, 0, kb16, cosT, sinT, k_gamma, k_beta, 1, 1, S);
    post_wave<<<(S * H + 3) / 4, 256, 0, stream>>>(
        qb16, 1, qb16, cosT, sinT, nullptr, nullptr, H, 0, S * H);

    // 6) logits (barrier-free head loop, reg-resident k + reg-dbuf q)
    logits_mfma<<<dim3(S / 128, S / 64), 256, 0, stream>>>(
        (const short*)qb16, (const short*)kb16, wbuf, out_logits);

    // 7) top-k indices (radix select, written as float)
    topk_select<<<S, 256, 0, stream>>>(out_logits, out_idx);
}

// Round 8
// 458.184 us; speedup vs baseline: 1.2204x; 1.2204x over previous
//
#include <hip/hip_runtime.h>
#include <hip/hip_bf16.h>
#include <math.h>

#define S 4096
#define H 32
#define D 128
#define QLR 1536
#define HID 2048
#define TOPK_N 2048
#define NEGF (-1e30f)
#define KW_N 160

typedef __attribute__((ext_vector_type(8))) short bf16x8;
typedef __attribute__((ext_vector_type(4))) float f32x4;

__device__ __forceinline__ void async_copy16(const void* g, void* l) {
    __builtin_amdgcn_global_load_lds(
        (const __attribute__((address_space(1))) unsigned int*)g,
        (__attribute__((address_space(3))) unsigned int*)l,
        16, 0, 0);
}

__device__ __forceinline__ unsigned short bf16bits(float f) {
    __hip_bfloat16 h = __float2bfloat16(f);
    return *(unsigned short*)&h;
}

__device__ __forceinline__ float bits2f(unsigned short u) {
    unsigned v = ((unsigned)u) << 16;
    return __uint_as_float(v);
}

// raw barrier with scheduling fence (no vmcnt drain, unlike __syncthreads)
__device__ __forceinline__ void block_bar() {
    __builtin_amdgcn_sched_barrier(0);
    __builtin_amdgcn_s_barrier();
    __builtin_amdgcn_sched_barrier(0);
}

// ---------------------------------------------------------------------------
// Cast f32 -> bf16 (elementwise, float4 granular)
// ---------------------------------------------------------------------------
__global__ __launch_bounds__(256) void cast_bf16_kernel(
    const float* __restrict__ in, __hip_bfloat16* __restrict__ out, int n4)
{
    int i = blockIdx.x * blockDim.x + threadIdx.x;
    if (i < n4) {
        float4 v = ((const float4*)in)[i];
        ushort4 pack;
        pack.x = bf16bits(v.x);
        pack.y = bf16bits(v.y);
        pack.z = bf16bits(v.z);
        pack.w = bf16bits(v.w);
        *(ushort4*)(out + (size_t)i * 4) = pack;
    }
}

__global__ __launch_bounds__(256) void zero_f32(float* __restrict__ p, int n)
{
    int i = blockIdx.x * blockDim.x + threadIdx.x;
    if (i < n) p[i] = 0.0f;
}

// ---------------------------------------------------------------------------
// Transpose + cast: Wq (1536 x 4096 f32) -> WqT (4096 x 1536 bf16)
// ---------------------------------------------------------------------------
__global__ __launch_bounds__(256) void transpose_cast_kernel(
    const float* __restrict__ in, __hip_bfloat16* __restrict__ out)
{
    __shared__ float sm[32][33];
    const int nb = blockIdx.x;
    const int kb = blockIdx.y;
    const int t = threadIdx.x;
    const int j = t & 31, i0 = t >> 5;
#pragma unroll
    for (int u = 0; u < 4; ++u) {
        int i = i0 + u * 8;
        sm[i][j] = in[(size_t)(kb * 32 + i) * 4096 + nb * 32 + j];
    }
    __syncthreads();
#pragma unroll
    for (int u = 0; u < 4; ++u) {
        int i = i0 + u * 8;
        out[(size_t)(nb * 32 + i) * 1536 + kb * 32 + j] = __float2bfloat16(sm[j][i]);
    }
}

// ---------------------------------------------------------------------------
// Build WkpT (160 x 2048 bf16): rows 0..127 = Wk^T, rows 128..159 = (Wp/64)^T
// ---------------------------------------------------------------------------
__global__ __launch_bounds__(256) void build_wkpT(
    const float* __restrict__ Wk, const float* __restrict__ Wp,
    __hip_bfloat16* __restrict__ WkpT)
{
    int g = blockIdx.x * blockDim.x + threadIdx.x;
    if (g >= KW_N * HID) return;
    int n = g / HID, k = g % HID;
    float v = (n < 128) ? Wk[(size_t)k * 128 + n]
                        : Wp[(size_t)k * 32 + (n - 128)] * 0.015625f;
    WkpT[g] = __float2bfloat16(v);
}

// ---------------------------------------------------------------------------
// Fused k/w projection, split-K=4 MFMA (atomicAdd f32 partials).
// ---------------------------------------------------------------------------
__device__ __forceinline__ void kw_stage(
    const short* __restrict__ hb, const short* __restrict__ WkpT,
    int mt, int koff, int rhi, int e, int wave, short* bufA, short* bufB)
{
#pragma unroll
    for (int it = 0; it < 4; ++it) {
        int r = it * 16 + rhi;
        async_copy16(hb + (size_t)(mt * 64 + r) * HID + koff + e * 8,
                     (void*)(bufA + it * 2048 + wave * 512));
    }
#pragma unroll
    for (int it = 0; it < 10; ++it) {
        int r = it * 16 + rhi;
        async_copy16(WkpT + (size_t)r * HID + koff + e * 8,
                     (void*)(bufB + it * 2048 + wave * 512));
    }
}

__global__ __launch_bounds__(256) void kw_mfma(
    const short* __restrict__ hb,
    const short* __restrict__ WkpT,
    float* __restrict__ kf32,
    float* __restrict__ wbuf)
{
    const int mt = blockIdx.x;
    const int kbase = blockIdx.y * 512;      // split-K = 4, 512 K per block
    const int tid = threadIdx.x;
    const int wave = tid >> 6, lane = tid & 63, grp = lane >> 4, lm = lane & 15;
    __shared__ short As[2][64 * 128];        // 2 x 16KB
    __shared__ short Bs[2][KW_N * 128];      // 2 x 40KB

    const int rhi = tid >> 4;
    const int e = (tid & 15) ^ rhi;

    kw_stage(hb, WkpT, mt, kbase, rhi, e, wave, As[0], Bs[0]);

    f32x4 acc[10] = {};
    int cur = 0;
    for (int kc = 0; kc < 4; ++kc) {
        __syncthreads();
        if (kc < 3)
            kw_stage(hb, WkpT, mt, kbase + (kc + 1) * 128, rhi, e, wave,
                     As[cur ^ 1], Bs[cur ^ 1]);
#pragma unroll
        for (int k4 = 0; k4 < 4; ++k4) {
            int ch = ((k4 << 2) + grp) ^ lm;
            bf16x8 a = *(const bf16x8*)(As[cur] + (wave * 16 + lm) * 128 + ch * 8);
#pragma unroll
            for (int n = 0; n < 10; ++n) {
                bf16x8 b = *(const bf16x8*)(Bs[cur] + (n * 16 + lm) * 128 + ch * 8);
                acc[n] = __builtin_amdgcn_mfma_f32_16x16x32_bf16(a, b, acc[n], 0, 0, 0);
            }
        }
        cur ^= 1;
    }

#pragma unroll
    for (int n = 0; n < 10; ++n) {
#pragma unroll
        for (int r = 0; r < 4; ++r) {
            int row = mt * 64 + wave * 16 + grp * 4 + r;
            int col = n * 16 + lm;
            if (n < 8) atomicAdd(&kf32[(size_t)row * 128 + col], acc[n][r]);
            else       atomicAdd(&wbuf[(size_t)row * 32 + (col - 128)], acc[n][r]);
        }
    }
}

// ---------------------------------------------------------------------------
// bf16 MFMA GEMM, B^T layout (q projection). BK=64, dbuf, XOR-swizzled.
// ---------------------------------------------------------------------------
__device__ __forceinline__ void gemm_stage64(
    const short* __restrict__ Ag, const short* __restrict__ Bg,
    int row0, int col0, int K, int kc, int tid, short* as, short* bs)
{
    const int w = tid >> 6, lane = tid & 63;
    const int rsub = lane >> 3;               // row within 8-row group
    const int c = (lane & 7) ^ rsub;          // swizzled source chunk
#pragma unroll
    for (int i = 0; i < 4; ++i) {
        int r = w * 32 + i * 8 + rsub;
        async_copy16(Ag + (size_t)(row0 + r) * K + kc + c * 8,
                     (void*)(as + (w * 32 + i * 8) * 64));
        async_copy16(Bg + (size_t)(col0 + r) * K + kc + c * 8,
                     (void*)(bs + (w * 32 + i * 8) * 64));
    }
}

__global__ __launch_bounds__(256, 2) void gemm_bf16_bt(
    const __hip_bfloat16* __restrict__ A, const __hip_bfloat16* __restrict__ BT,
    __hip_bfloat16* __restrict__ C, int M, int N, int K)
{
    __shared__ short As[2][128 * 64];   // 2 x 16KB
    __shared__ short Bs[2][128 * 64];   // 2 x 16KB
    const int tid = threadIdx.x;
    const int wave = tid >> 6, lane = tid & 63, grp = lane >> 4, lm = lane & 15;
    const int row0 = blockIdx.y * 128, col0 = blockIdx.x * 128;
    const short* Ag = (const short*)A;
    const short* Bg = (const short*)BT;

    f32x4 acc[2][8] = {};

    gemm_stage64(Ag, Bg, row0, col0, K, 0, tid, As[0], Bs[0]);
    int cur = 0;
    for (int kc = 0; kc < K; kc += 64) {
        __syncthreads();                 // buf[cur] ready; buf[cur^1] reads done
        if (kc + 64 < K)
            gemm_stage64(Ag, Bg, row0, col0, K, kc + 64, tid,
                         As[cur ^ 1], Bs[cur ^ 1]);
#pragma unroll
        for (int k2 = 0; k2 < 2; ++k2) {
            int pos = ((k2 << 2) + grp) ^ (lm & 7);
            bf16x8 a0 = *(const bf16x8*)(As[cur] + (wave * 32 + lm) * 64 + pos * 8);
            bf16x8 a1 = *(const bf16x8*)(As[cur] + (wave * 32 + 16 + lm) * 64 + pos * 8);
#pragma unroll
            for (int c = 0; c < 8; ++c) {
                bf16x8 b = *(const bf16x8*)(Bs[cur] + (c * 16 + lm) * 64 + pos * 8);
                acc[0][c] = __builtin_amdgcn_mfma_f32_16x16x32_bf16(a0, b, acc[0][c], 0, 0, 0);
                acc[1][c] = __builtin_amdgcn_mfma_f32_16x16x32_bf16(a1, b, acc[1][c], 0, 0, 0);
            }
        }
        cur ^= 1;
    }
#pragma unroll
    for (int t = 0; t < 2; ++t)
#pragma unroll
        for (int c = 0; c < 8; ++c)
#pragma unroll
            for (int r = 0; r < 4; ++r) {
                int rr = row0 + wave * 32 + t * 16 + grp * 4 + r;
                int cc = col0 + c * 16 + lm;
                C[(size_t)rr * N + cc] = __float2bfloat16(acc[t][c][r]);
            }
}

// ---------------------------------------------------------------------------
// RoPE cos/sin table
// ---------------------------------------------------------------------------
__global__ void sincos_table_kernel(const int* __restrict__ positions,
                                    float* __restrict__ cosT, float* __restrict__ sinT)
{
    int g = blockIdx.x * blockDim.x + threadIdx.x;
    if (g >= S * 32) return;
    int s = g >> 5;
    int p = g & 31;
    float inv = exp2f(-13.28771237954945f * (float)(2 * p) * (1.0f / 64.0f));
    float ang = (float)positions[s] * inv;
    float sv, cv;
    sincosf(ang, &sv, &cv);
    cosT[g] = cv;
    sinT[g] = sv;
}

// ---------------------------------------------------------------------------
// Wave-per-row postprocess: optional LN, RoPE, FWHT. No barriers, no LDS.
// ---------------------------------------------------------------------------
__global__ __launch_bounds__(256) void post_wave(
    const void* __restrict__ in, int in_bf16, __hip_bfloat16* __restrict__ outb,
    const float* __restrict__ cosT, const float* __restrict__ sinT,
    const float* __restrict__ gamma, const float* __restrict__ beta,
    int heads, int do_ln, int nrows)
{
    const int row = blockIdx.x * 4 + (threadIdx.x >> 6);
    if (row >= nrows) return;
    const int l = threadIdx.x & 63;
    const int srow = row / heads;

    float a, b;
    if (in_bf16) {
        unsigned pr = ((const unsigned*)in)[(size_t)row * 64 + l];
        a = bits2f((unsigned short)(pr & 0xffff));
        b = bits2f((unsigned short)(pr >> 16));
    } else {
        float2 v = ((const float2*)in)[(size_t)row * 64 + l];
        a = v.x; b = v.y;
    }

    if (do_ln) {
        float s = a + b;
#pragma unroll
        for (int o = 1; o < 64; o <<= 1) s += __shfl_xor(s, o);
        float mu = s * (1.0f / 128.0f);
        float da = a - mu, db = b - mu;
        float sq = da * da + db * db;
#pragma unroll
        for (int o = 1; o < 64; o <<= 1) sq += __shfl_xor(sq, o);
        float rs = rsqrtf(sq * (1.0f / 128.0f) + 1e-6f);
        float2 g = ((const float2*)gamma)[l];
        float2 bt = ((const float2*)beta)[l];
        a = da * rs * g.x + bt.x;
        b = db * rs * g.y + bt.y;
    }

    if (l < 32) {
        float c = cosT[(size_t)srow * 32 + l];
        float sn = sinT[(size_t)srow * 32 + l];
        float xe = a, xo = b;
        a = xe * c - xo * sn;
        b = xe * sn + xo * c;
    }

    {
        float na = a + b, nb = a - b;
        a = na; b = nb;
    }
#pragma unroll
    for (int m = 1; m < 64; m <<= 1) {
        float pa = __shfl_xor(a, m);
        float pb = __shfl_xor(b, m);
        if (l & m) { a = pa - a; b = pb - b; }
        else       { a = a + pa; b = b + pb; }
    }

    const float sc = 0.08838834764831845f;
    unsigned outp = (unsigned)bf16bits(a * sc) | ((unsigned)bf16bits(b * sc) << 16);
    ((unsigned*)outb)[(size_t)row * 64 + l] = outp;
}

// ---------------------------------------------------------------------------
// MFMA logits v4: v2 dataflow (LDS-staged per-head A, reg-resident k) with
// counted-vmcnt raw barriers (T3/T4 minimum): loads stay 2 heads deep in
// flight across barriers; vmcnt(4) retires only the head being computed.
// Single vmcnt(0) drain in the whole loop (h=31).
// Block 64x128, 4 waves (wave tile 32x64), LDS 41KB -> 3 blocks/CU.
// ---------------------------------------------------------------------------
__global__ __launch_bounds__(256, 3) void logits_mfma(
    const short* __restrict__ qb,   // S x (H*D) bf16 bits
    const short* __restrict__ kb,   // S x D bf16 bits
    const float* __restrict__ w,    // S x H
    float* __restrict__ out)
{
    const int bx = blockIdx.x;      // 0..31 col tiles (128 wide)
    const int by = blockIdx.y;      // 0..63 row tiles (64 tall)
    const int row0 = by * 64, col0 = bx * 128;
    const int tid = threadIdx.x;

    if (2 * bx > by) {
        const float4 n4 = make_float4(NEGF, NEGF, NEGF, NEGF);
        int c = (tid & 31) * 4;
        for (int r = tid >> 5; r < 64; r += 8)
            *(float4*)&out[(size_t)(row0 + r) * S + col0 + c] = n4;
        return;
    }

    __shared__ short BsAs[128 * 128];   // 32KB: k tile, then As[2] overlay
    __shared__ float Ws[64 * 33];       // w block, padded

    const int wave = tid >> 6, lane = tid & 63, grp = lane >> 4, lm = lane & 15;
    const int wr = wave >> 1, wc = wave & 1;
    const int rhi = tid >> 4;
    const int e = (tid & 15) ^ rhi;

    // stage k tile once (into the overlay region)
#pragma unroll
    for (int it = 0; it < 8; ++it) {
        int r = it * 16 + rhi;
        async_copy16(kb + (size_t)(col0 + r) * D + e * 8,
                     (void*)(BsAs + it * 2048 + wave * 512));
    }
    // stage w block (64 rows x 32 heads) into padded LDS
    for (int i = tid; i < 64 * 32; i += 256) {
        int r = i >> 5, h = i & 31;
        Ws[r * 33 + h] = w[(size_t)row0 * H + i];
    }
    __syncthreads();   // full drain: k + Ws ready

    // cache all k fragments in registers
    bf16x8 bfrag[4][4];
#pragma unroll
    for (int c = 0; c < 4; ++c)
#pragma unroll
        for (int kc = 0; kc < 4; ++kc)
            bfrag[c][kc] = *(const bf16x8*)(
                BsAs + (wc * 64 + c * 16 + lm) * 128 + (((kc << 2) + grp) ^ lm) * 8);
    __syncthreads();   // all waves done reading k tile -> overlay reusable

    short* As0 = BsAs;
    short* As1 = BsAs + 64 * 128;

    // stage head h's 64x128 A-tile: 4 x 16B async per thread
    auto stageA = [&](short* dst, int h) {
#pragma unroll
        for (int it = 0; it < 4; ++it) {
            int r = it * 16 + rhi;
            async_copy16(qb + (size_t)(row0 + r) * (H * D) + h * D + e * 8,
                         (void*)(dst + it * 2048 + wave * 512));
        }
    };

    f32x4 accP[2][4] = {};

    auto computeH = [&](const short* Acur, int h) {
        f32x4 accH[2][4] = {};
        __builtin_amdgcn_s_setprio(1);
#pragma unroll
        for (int kc = 0; kc < 4; ++kc) {
            int ch = ((kc << 2) + grp) ^ lm;
            bf16x8 a0 = *(const bf16x8*)(Acur + (wr * 32 + lm) * 128 + ch * 8);
            bf16x8 a1 = *(const bf16x8*)(Acur + (wr * 32 + 16 + lm) * 128 + ch * 8);
#pragma unroll
            for (int c = 0; c < 4; ++c) {
                accH[0][c] = __builtin_amdgcn_mfma_f32_16x16x32_bf16(a0, bfrag[c][kc], accH[0][c], 0, 0, 0);
                accH[1][c] = __builtin_amdgcn_mfma_f32_16x16x32_bf16(a1, bfrag[c][kc], accH[1][c], 0, 0, 0);
            }
        }
        __builtin_amdgcn_s_setprio(0);
#pragma unroll
        for (int t = 0; t < 2; ++t)
#pragma unroll
            for (int r = 0; r < 4; ++r) {
                float wv = Ws[(wr * 32 + t * 16 + grp * 4 + r) * 33 + h];
#pragma unroll
                for (int c = 0; c < 4; ++c)
                    accP[t][c][r] += wv * fmaxf(accH[t][c][r], 0.0f);
            }
    };

    // prologue: 2 heads in flight
    stageA(As0, 0);
    stageA(As1, 1);

    for (int h = 0; h < H - 1; ++h) {
        // retire stage(h): 4 loads of stage(h+1) may remain in flight
        asm volatile("s_waitcnt vmcnt(4)" ::: "memory");
        block_bar();                       // stage(h) visible to all waves
        computeH((h & 1) ? As1 : As0, h);
        block_bar();                       // all waves done reading buf[h&1]
        if (h + 2 < H)
            stageA((h & 1) ? As1 : As0, h + 2);
    }
    // last head: only stage(31) outstanding
    asm volatile("s_waitcnt vmcnt(0)" ::: "memory");
    block_bar();
    computeH(As1, H - 1);

#pragma unroll
    for (int t = 0; t < 2; ++t)
#pragma unroll
        for (int c = 0; c < 4; ++c)
#pragma unroll
            for (int r = 0; r < 4; ++r) {
                int rr = row0 + wr * 32 + t * 16 + grp * 4 + r;
                int cc = col0 + wc * 64 + c * 16 + lm;
                out[(size_t)rr * S + cc] = (cc <= rr) ? accP[t][c][r] : NEGF;
            }
}

// ---------------------------------------------------------------------------
// Top-k via 4-round radix select (11-bit digits over unique 44-bit keys).
// ---------------------------------------------------------------------------
__device__ __forceinline__ unsigned mono32(float f)
{
    unsigned u = __float_as_uint(f);
    return (u & 0x80000000u) ? ~u : (u | 0x80000000u);
}

__global__ __launch_bounds__(256) void topk_select(
    const float* __restrict__ logits, float* __restrict__ out_idx)
{
    const int row = blockIdx.x;
    const int tid = threadIdx.x;
    const int valid = row + 1;
    float* orow = out_idx + (size_t)row * TOPK_N;

    if (valid <= TOPK_N) {
        for (int p = tid; p < TOPK_N; p += 256)
            orow[p] = (p < valid) ? (float)p : -1.0f;
        return;
    }

    __shared__ float vals[S];
    __shared__ unsigned hist[2048];
    __shared__ unsigned chunk[256];
    __shared__ unsigned long long sh_prefix;
    __shared__ int sh_rem;
    __shared__ unsigned sh_cnt;

    const float* lr = logits + (size_t)row * S;
    for (int j = tid; j < valid; j += 256) vals[j] = lr[j];
    if (tid == 0) { sh_prefix = 0ull; sh_rem = TOPK_N; sh_cnt = 0u; }
    __syncthreads();

    for (int rnd = 0; rnd < 4; ++rnd) {
        const int shift = 33 - 11 * rnd;
        for (int i = tid; i < 2048; i += 256) hist[i] = 0u;
        __syncthreads();
        const unsigned long long pref = sh_prefix;
        const int rem = sh_rem;
        const int hs = shift + 11;
        for (int j = tid; j < valid; j += 256) {
            unsigned long long key = (((unsigned long long)mono32(vals[j])) << 12)
                                   | (unsigned)(4095 - j);
            if ((key >> hs) == (pref >> hs))
                atomicAdd(&hist[(unsigned)(key >> shift) & 2047u], 1u);
        }
        __syncthreads();
        unsigned csum = 0;
#pragma unroll
        for (int d = 0; d < 8; ++d) csum += hist[tid * 8 + d];
        chunk[tid] = csum;
        __syncthreads();
        for (int off = 1; off < 256; off <<= 1) {
            unsigned v = (tid + off < 256) ? chunk[tid + off] : 0u;
            __syncthreads();
            chunk[tid] += v;
            __syncthreads();
        }
        unsigned A = (tid < 255) ? chunk[tid + 1] : 0u;
        for (int dd = 7; dd >= 0; --dd) {
            unsigned c = hist[tid * 8 + dd];
            if (c && A < (unsigned)rem && (unsigned)rem <= A + c) {
                sh_prefix = pref | ((unsigned long long)(tid * 8 + dd) << shift);
                sh_rem = rem - (int)A;
            }
            A += c;
        }
        __syncthreads();
    }

    const unsigned long long Kstar = sh_prefix;
    for (int j = tid; j < valid; j += 256) {
        unsigned long long key = (((unsigned long long)mono32(vals[j])) << 12)
                               | (unsigned)(4095 - j);
        if (key >= Kstar) {
            unsigned p = atomicAdd(&sh_cnt, 1u);
            orow[p] = (float)j;
        }
    }
}

// ---------------------------------------------------------------------------
extern "C" void kernel_launch(void* const* d_in, const int* in_sizes, int n_in,
                              void* d_out, int out_size, void* d_ws, size_t ws_size,
                              hipStream_t stream)
{
    const float* hidden    = (const float*)d_in[0];
    const float* q_lora    = (const float*)d_in[1];
    const int*   positions = (const int*)d_in[2];
    const float* Wq        = (const float*)d_in[3];
    const float* Wk        = (const float*)d_in[4];
    const float* k_gamma   = (const float*)d_in[5];
    const float* k_beta    = (const float*)d_in[6];
    const float* Wp        = (const float*)d_in[7];

    char* ws = (char*)d_ws;
    size_t off = 0;
    __hip_bfloat16* qb16 = (__hip_bfloat16*)(ws + off); off += (size_t)S * H * D * 2;
    __hip_bfloat16* qlb  = (__hip_bfloat16*)(ws + off); off += (size_t)S * QLR * 2;
    __hip_bfloat16* WqT  = (__hip_bfloat16*)(ws + off); off += (size_t)(H * D) * QLR * 2;
    __hip_bfloat16* hb   = (__hip_bfloat16*)(ws + off); off += (size_t)S * HID * 2;
    __hip_bfloat16* WkpT = (__hip_bfloat16*)(ws + off); off += (size_t)KW_N * HID * 2;
    float* kf32 = (float*)(ws + off); off += (size_t)S * D * 4;
    __hip_bfloat16* kb16 = (__hip_bfloat16*)(ws + off); off += (size_t)S * D * 2;
    float* wbuf = (float*)(ws + off); off += (size_t)S * H * 4;
    float* cosT = (float*)(ws + off); off += (size_t)S * 32 * 4;
    float* sinT = (float*)(ws + off); off += (size_t)S * 32 * 4;

    float* out_logits = (float*)d_out;
    float* out_idx = out_logits + (size_t)S * S;

    // 1) casts for the q GEMM
    cast_bf16_kernel<<<(S * QLR / 4 + 255) / 256, 256, 0, stream>>>(q_lora, qlb, S * QLR / 4);
    transpose_cast_kernel<<<dim3((H * D) / 32, QLR / 32), 256, 0, stream>>>(Wq, WqT);

    // 2) q = q_lora @ Wq  (bf16 MFMA, BK=64 dbuf)
    gemm_bf16_bt<<<dim3((H * D) / 128, S / 128), 256, 0, stream>>>(
        qlb, WqT, qb16, S, H * D, QLR);

    // 3) fused k/w projection, split-K=4 MFMA + f32 atomics
    cast_bf16_kernel<<<(S * HID / 4 + 255) / 256, 256, 0, stream>>>(hidden, hb, S * HID / 4);
    build_wkpT<<<(KW_N * HID + 255) / 256, 256, 0, stream>>>(Wk, Wp, WkpT);
    zero_f32<<<(S * D + 255) / 256, 256, 0, stream>>>(kf32, S * D);
    zero_f32<<<(S * H + 255) / 256, 256, 0, stream>>>(wbuf, S * H);
    kw_mfma<<<dim3(S / 64, 4), 256, 0, stream>>>(
        (const short*)hb, (const short*)WkpT, kf32, wbuf);

    // 4) RoPE trig table
    sincos_table_kernel<<<(S * 32) / 256, 256, 0, stream>>>(positions, cosT, sinT);

    // 5) k: LN + RoPE + FWHT -> bf16 ; q: RoPE + FWHT in place (bf16)
    post_wave<<<(S + 3) / 4, 256, 0, stream>>>(
        kf32, 0, kb16, cosT, sinT, k_gamma, k_beta, 1, 1, S);
    post_wave<<<(S * H + 3) / 4, 256, 0, stream>>>(
        qb16, 1, qb16, cosT, sinT, nullptr, nullptr, H, 0, S * H);

    // 6) logits (counted-vmcnt pipelined head loop)
    logits_mfma<<<dim3(S / 128, S / 64), 256, 0, stream>>>(
        (const short*)qb16, (const short*)kb16, wbuf, out_logits);

    // 7) top-k indices (radix select, written as float)
    topk_select<<<S, 256, 0, stream>>>(out_logits, out_idx);
}

// Round 9
// 434.505 us; speedup vs baseline: 1.2869x; 1.0545x over previous
//
#include <hip/hip_runtime.h>
#include <hip/hip_bf16.h>
#include <math.h>

#define S 4096
#define H 32
#define D 128
#define QLR 1536
#define HID 2048
#define TOPK_N 2048
#define NEGF (-1e30f)
#define KW_N 160

typedef __attribute__((ext_vector_type(8))) short bf16x8;
typedef __attribute__((ext_vector_type(4))) float f32x4;

__device__ __forceinline__ void async_copy16(const void* g, void* l) {
    __builtin_amdgcn_global_load_lds(
        (const __attribute__((address_space(1))) unsigned int*)g,
        (__attribute__((address_space(3))) unsigned int*)l,
        16, 0, 0);
}

__device__ __forceinline__ unsigned short bf16bits(float f) {
    __hip_bfloat16 h = __float2bfloat16(f);
    return *(unsigned short*)&h;
}

__device__ __forceinline__ float bits2f(unsigned short u) {
    unsigned v = ((unsigned)u) << 16;
    return __uint_as_float(v);
}

// ---------------------------------------------------------------------------
// Cast f32 -> bf16 (elementwise, float4 granular)
// ---------------------------------------------------------------------------
__global__ __launch_bounds__(256) void cast_bf16_kernel(
    const float* __restrict__ in, __hip_bfloat16* __restrict__ out, int n4)
{
    int i = blockIdx.x * blockDim.x + threadIdx.x;
    if (i < n4) {
        float4 v = ((const float4*)in)[i];
        ushort4 pack;
        pack.x = bf16bits(v.x);
        pack.y = bf16bits(v.y);
        pack.z = bf16bits(v.z);
        pack.w = bf16bits(v.w);
        *(ushort4*)(out + (size_t)i * 4) = pack;
    }
}

__global__ __launch_bounds__(256) void zero_f32(float* __restrict__ p, int n)
{
    int i = blockIdx.x * blockDim.x + threadIdx.x;
    if (i < n) p[i] = 0.0f;
}

// ---------------------------------------------------------------------------
// Transpose + cast: Wq (1536 x 4096 f32) -> WqT (4096 x 1536 bf16)
// ---------------------------------------------------------------------------
__global__ __launch_bounds__(256) void transpose_cast_kernel(
    const float* __restrict__ in, __hip_bfloat16* __restrict__ out)
{
    __shared__ float sm[32][33];
    const int nb = blockIdx.x;
    const int kb = blockIdx.y;
    const int t = threadIdx.x;
    const int j = t & 31, i0 = t >> 5;
#pragma unroll
    for (int u = 0; u < 4; ++u) {
        int i = i0 + u * 8;
        sm[i][j] = in[(size_t)(kb * 32 + i) * 4096 + nb * 32 + j];
    }
    __syncthreads();
#pragma unroll
    for (int u = 0; u < 4; ++u) {
        int i = i0 + u * 8;
        out[(size_t)(nb * 32 + i) * 1536 + kb * 32 + j] = __float2bfloat16(sm[j][i]);
    }
}

// ---------------------------------------------------------------------------
// Build WkpT (160 x 2048 bf16): rows 0..127 = Wk^T, rows 128..159 = (Wp/64)^T
// ---------------------------------------------------------------------------
__global__ __launch_bounds__(256) void build_wkpT(
    const float* __restrict__ Wk, const float* __restrict__ Wp,
    __hip_bfloat16* __restrict__ WkpT)
{
    int g = blockIdx.x * blockDim.x + threadIdx.x;
    if (g >= KW_N * HID) return;
    int n = g / HID, k = g % HID;
    float v = (n < 128) ? Wk[(size_t)k * 128 + n]
                        : Wp[(size_t)k * 32 + (n - 128)] * 0.015625f;
    WkpT[g] = __float2bfloat16(v);
}

// ---------------------------------------------------------------------------
// Fused k/w projection, split-K=4 MFMA (atomicAdd f32 partials).
// ---------------------------------------------------------------------------
__device__ __forceinline__ void kw_stage(
    const short* __restrict__ hb, const short* __restrict__ WkpT,
    int mt, int koff, int rhi, int e, int wave, short* bufA, short* bufB)
{
#pragma unroll
    for (int it = 0; it < 4; ++it) {
        int r = it * 16 + rhi;
        async_copy16(hb + (size_t)(mt * 64 + r) * HID + koff + e * 8,
                     (void*)(bufA + it * 2048 + wave * 512));
    }
#pragma unroll
    for (int it = 0; it < 10; ++it) {
        int r = it * 16 + rhi;
        async_copy16(WkpT + (size_t)r * HID + koff + e * 8,
                     (void*)(bufB + it * 2048 + wave * 512));
    }
}

__global__ __launch_bounds__(256) void kw_mfma(
    const short* __restrict__ hb,
    const short* __restrict__ WkpT,
    float* __restrict__ kf32,
    float* __restrict__ wbuf)
{
    const int mt = blockIdx.x;
    const int kbase = blockIdx.y * 512;      // split-K = 4, 512 K per block
    const int tid = threadIdx.x;
    const int wave = tid >> 6, lane = tid & 63, grp = lane >> 4, lm = lane & 15;
    __shared__ short As[2][64 * 128];        // 2 x 16KB
    __shared__ short Bs[2][KW_N * 128];      // 2 x 40KB

    const int rhi = tid >> 4;
    const int e = (tid & 15) ^ rhi;

    kw_stage(hb, WkpT, mt, kbase, rhi, e, wave, As[0], Bs[0]);

    f32x4 acc[10] = {};
    int cur = 0;
    for (int kc = 0; kc < 4; ++kc) {
        __syncthreads();
        if (kc < 3)
            kw_stage(hb, WkpT, mt, kbase + (kc + 1) * 128, rhi, e, wave,
                     As[cur ^ 1], Bs[cur ^ 1]);
#pragma unroll
        for (int k4 = 0; k4 < 4; ++k4) {
            int ch = ((k4 << 2) + grp) ^ lm;
            bf16x8 a = *(const bf16x8*)(As[cur] + (wave * 16 + lm) * 128 + ch * 8);
#pragma unroll
            for (int n = 0; n < 10; ++n) {
                bf16x8 b = *(const bf16x8*)(Bs[cur] + (n * 16 + lm) * 128 + ch * 8);
                acc[n] = __builtin_amdgcn_mfma_f32_16x16x32_bf16(a, b, acc[n], 0, 0, 0);
            }
        }
        cur ^= 1;
    }

#pragma unroll
    for (int n = 0; n < 10; ++n) {
#pragma unroll
        for (int r = 0; r < 4; ++r) {
            int row = mt * 64 + wave * 16 + grp * 4 + r;
            int col = n * 16 + lm;
            if (n < 8) atomicAdd(&kf32[(size_t)row * 128 + col], acc[n][r]);
            else       atomicAdd(&wbuf[(size_t)row * 32 + (col - 128)], acc[n][r]);
        }
    }
}

// ---------------------------------------------------------------------------
// bf16 MFMA GEMM, B^T layout (q projection). BK=64, dbuf, XOR-swizzled.
// ---------------------------------------------------------------------------
__device__ __forceinline__ void gemm_stage64(
    const short* __restrict__ Ag, const short* __restrict__ Bg,
    int row0, int col0, int K, int kc, int tid, short* as, short* bs)
{
    const int w = tid >> 6, lane = tid & 63;
    const int rsub = lane >> 3;               // row within 8-row group
    const int c = (lane & 7) ^ rsub;          // swizzled source chunk
#pragma unroll
    for (int i = 0; i < 4; ++i) {
        int r = w * 32 + i * 8 + rsub;
        async_copy16(Ag + (size_t)(row0 + r) * K + kc + c * 8,
                     (void*)(as + (w * 32 + i * 8) * 64));
        async_copy16(Bg + (size_t)(col0 + r) * K + kc + c * 8,
                     (void*)(bs + (w * 32 + i * 8) * 64));
    }
}

__global__ __launch_bounds__(256, 2) void gemm_bf16_bt(
    const __hip_bfloat16* __restrict__ A, const __hip_bfloat16* __restrict__ BT,
    __hip_bfloat16* __restrict__ C, int M, int N, int K)
{
    __shared__ short As[2][128 * 64];   // 2 x 16KB
    __shared__ short Bs[2][128 * 64];   // 2 x 16KB
    const int tid = threadIdx.x;
    const int wave = tid >> 6, lane = tid & 63, grp = lane >> 4, lm = lane & 15;
    const int row0 = blockIdx.y * 128, col0 = blockIdx.x * 128;
    const short* Ag = (const short*)A;
    const short* Bg = (const short*)BT;

    f32x4 acc[2][8] = {};

    gemm_stage64(Ag, Bg, row0, col0, K, 0, tid, As[0], Bs[0]);
    int cur = 0;
    for (int kc = 0; kc < K; kc += 64) {
        __syncthreads();                 // buf[cur] ready; buf[cur^1] reads done
        if (kc + 64 < K)
            gemm_stage64(Ag, Bg, row0, col0, K, kc + 64, tid,
                         As[cur ^ 1], Bs[cur ^ 1]);
#pragma unroll
        for (int k2 = 0; k2 < 2; ++k2) {
            int pos = ((k2 << 2) + grp) ^ (lm & 7);
            bf16x8 a0 = *(const bf16x8*)(As[cur] + (wave * 32 + lm) * 64 + pos * 8);
            bf16x8 a1 = *(const bf16x8*)(As[cur] + (wave * 32 + 16 + lm) * 64 + pos * 8);
#pragma unroll
            for (int c = 0; c < 8; ++c) {
                bf16x8 b = *(const bf16x8*)(Bs[cur] + (c * 16 + lm) * 64 + pos * 8);
                acc[0][c] = __builtin_amdgcn_mfma_f32_16x16x32_bf16(a0, b, acc[0][c], 0, 0, 0);
                acc[1][c] = __builtin_amdgcn_mfma_f32_16x16x32_bf16(a1, b, acc[1][c], 0, 0, 0);
            }
        }
        cur ^= 1;
    }
#pragma unroll
    for (int t = 0; t < 2; ++t)
#pragma unroll
        for (int c = 0; c < 8; ++c)
#pragma unroll
            for (int r = 0; r < 4; ++r) {
                int rr = row0 + wave * 32 + t * 16 + grp * 4 + r;
                int cc = col0 + c * 16 + lm;
                C[(size_t)rr * N + cc] = __float2bfloat16(acc[t][c][r]);
            }
}

// ---------------------------------------------------------------------------
// RoPE cos/sin table
// ---------------------------------------------------------------------------
__global__ void sincos_table_kernel(const int* __restrict__ positions,
                                    float* __restrict__ cosT, float* __restrict__ sinT)
{
    int g = blockIdx.x * blockDim.x + threadIdx.x;
    if (g >= S * 32) return;
    int s = g >> 5;
    int p = g & 31;
    float inv = exp2f(-13.28771237954945f * (float)(2 * p) * (1.0f / 64.0f));
    float ang = (float)positions[s] * inv;
    float sv, cv;
    sincosf(ang, &sv, &cv);
    cosT[g] = cv;
    sinT[g] = sv;
}

// ---------------------------------------------------------------------------
// Wave-per-row postprocess: optional LN, RoPE, FWHT. No barriers, no LDS.
// ---------------------------------------------------------------------------
__global__ __launch_bounds__(256) void post_wave(
    const void* __restrict__ in, int in_bf16, __hip_bfloat16* __restrict__ outb,
    const float* __restrict__ cosT, const float* __restrict__ sinT,
    const float* __restrict__ gamma, const float* __restrict__ beta,
    int heads, int do_ln, int nrows)
{
    const int row = blockIdx.x * 4 + (threadIdx.x >> 6);
    if (row >= nrows) return;
    const int l = threadIdx.x & 63;
    const int srow = row / heads;

    float a, b;
    if (in_bf16) {
        unsigned pr = ((const unsigned*)in)[(size_t)row * 64 + l];
        a = bits2f((unsigned short)(pr & 0xffff));
        b = bits2f((unsigned short)(pr >> 16));
    } else {
        float2 v = ((const float2*)in)[(size_t)row * 64 + l];
        a = v.x; b = v.y;
    }

    if (do_ln) {
        float s = a + b;
#pragma unroll
        for (int o = 1; o < 64; o <<= 1) s += __shfl_xor(s, o);
        float mu = s * (1.0f / 128.0f);
        float da = a - mu, db = b - mu;
        float sq = da * da + db * db;
#pragma unroll
        for (int o = 1; o < 64; o <<= 1) sq += __shfl_xor(sq, o);
        float rs = rsqrtf(sq * (1.0f / 128.0f) + 1e-6f);
        float2 g = ((const float2*)gamma)[l];
        float2 bt = ((const float2*)beta)[l];
        a = da * rs * g.x + bt.x;
        b = db * rs * g.y + bt.y;
    }

    if (l < 32) {
        float c = cosT[(size_t)srow * 32 + l];
        float sn = sinT[(size_t)srow * 32 + l];
        float xe = a, xo = b;
        a = xe * c - xo * sn;
        b = xe * sn + xo * c;
    }

    {
        float na = a + b, nb = a - b;
        a = na; b = nb;
    }
#pragma unroll
    for (int m = 1; m < 64; m <<= 1) {
        float pa = __shfl_xor(a, m);
        float pb = __shfl_xor(b, m);
        if (l & m) { a = pa - a; b = pb - b; }
        else       { a = a + pa; b = b + pb; }
    }

    const float sc = 0.08838834764831845f;
    unsigned outp = (unsigned)bf16bits(a * sc) | ((unsigned)bf16bits(b * sc) << 16);
    ((unsigned*)outb)[(size_t)row * 64 + l] = outp;
}

// ---------------------------------------------------------------------------
// MFMA logits v5: v2 dataflow with the TRUE single-barrier T3 pattern.
// Per head: ONE __syncthreads (drains stage(h), separates compute(h-1)'s
// reads from stage(h+1)'s overwrite), then issue stage(h+1), then compute(h).
// The prefetch is in flight across the entire compute phase and is drained
// only at the NEXT head's barrier. No raw barriers, no sched fences --
// compiler keeps full scheduling freedom (m141 lesson from v4's regression).
// Block 64x128, 4 waves (wave tile 32x64), LDS 41KB -> 3 blocks/CU.
// ---------------------------------------------------------------------------
__global__ __launch_bounds__(256, 3) void logits_mfma(
    const short* __restrict__ qb,   // S x (H*D) bf16 bits
    const short* __restrict__ kb,   // S x D bf16 bits
    const float* __restrict__ w,    // S x H
    float* __restrict__ out)
{
    const int bx = blockIdx.x;      // 0..31 col tiles (128 wide)
    const int by = blockIdx.y;      // 0..63 row tiles (64 tall)
    const int row0 = by * 64, col0 = bx * 128;
    const int tid = threadIdx.x;

    if (2 * bx > by) {
        const float4 n4 = make_float4(NEGF, NEGF, NEGF, NEGF);
        int c = (tid & 31) * 4;
        for (int r = tid >> 5; r < 64; r += 8)
            *(float4*)&out[(size_t)(row0 + r) * S + col0 + c] = n4;
        return;
    }

    __shared__ short BsAs[128 * 128];   // 32KB: k tile, then As[2] overlay
    __shared__ float Ws[64 * 33];       // w block, padded

    const int wave = tid >> 6, lane = tid & 63, grp = lane >> 4, lm = lane & 15;
    const int wr = wave >> 1, wc = wave & 1;
    const int rhi = tid >> 4;
    const int e = (tid & 15) ^ rhi;

    // stage k tile once (into the overlay region)
#pragma unroll
    for (int it = 0; it < 8; ++it) {
        int r = it * 16 + rhi;
        async_copy16(kb + (size_t)(col0 + r) * D + e * 8,
                     (void*)(BsAs + it * 2048 + wave * 512));
    }
    // stage w block (64 rows x 32 heads) into padded LDS
    for (int i = tid; i < 64 * 32; i += 256) {
        int r = i >> 5, h = i & 31;
        Ws[r * 33 + h] = w[(size_t)row0 * H + i];
    }
    __syncthreads();   // k + Ws ready

    // cache all k fragments in registers
    bf16x8 bfrag[4][4];
#pragma unroll
    for (int c = 0; c < 4; ++c)
#pragma unroll
        for (int kc = 0; kc < 4; ++kc)
            bfrag[c][kc] = *(const bf16x8*)(
                BsAs + (wc * 64 + c * 16 + lm) * 128 + (((kc << 2) + grp) ^ lm) * 8);
    __syncthreads();   // all waves done reading k tile -> overlay reusable

    short* As0 = BsAs;
    short* As1 = BsAs + 64 * 128;

    // stage head h's 64x128 A-tile: 4 x 16B async per thread
    auto stageA = [&](short* dst, int h) {
#pragma unroll
        for (int it = 0; it < 4; ++it) {
            int r = it * 16 + rhi;
            async_copy16(qb + (size_t)(row0 + r) * (H * D) + h * D + e * 8,
                         (void*)(dst + it * 2048 + wave * 512));
        }
    };

    f32x4 accP[2][4] = {};

    auto computeH = [&](const short* Acur, int h) {
        f32x4 accH[2][4] = {};
        __builtin_amdgcn_s_setprio(1);
#pragma unroll
        for (int kc = 0; kc < 4; ++kc) {
            int ch = ((kc << 2) + grp) ^ lm;
            bf16x8 a0 = *(const bf16x8*)(Acur + (wr * 32 + lm) * 128 + ch * 8);
            bf16x8 a1 = *(const bf16x8*)(Acur + (wr * 32 + 16 + lm) * 128 + ch * 8);
#pragma unroll
            for (int c = 0; c < 4; ++c) {
                accH[0][c] = __builtin_amdgcn_mfma_f32_16x16x32_bf16(a0, bfrag[c][kc], accH[0][c], 0, 0, 0);
                accH[1][c] = __builtin_amdgcn_mfma_f32_16x16x32_bf16(a1, bfrag[c][kc], accH[1][c], 0, 0, 0);
            }
        }
        __builtin_amdgcn_s_setprio(0);
#pragma unroll
        for (int t = 0; t < 2; ++t)
#pragma unroll
            for (int r = 0; r < 4; ++r) {
                float wv = Ws[(wr * 32 + t * 16 + grp * 4 + r) * 33 + h];
#pragma unroll
                for (int c = 0; c < 4; ++c)
                    accP[t][c][r] += wv * fmaxf(accH[t][c][r], 0.0f);
            }
    };

    // prologue: stage head 0
    stageA(As0, 0);

    for (int h = 0; h < H; ++h) {
        __syncthreads();   // stage(h) landed (own-wave drain + rendezvous);
                           // compute(h-1) readers of buf[(h+1)&1] are done
        if (h + 1 < H)
            stageA((h & 1) ? As0 : As1, h + 1);   // in flight across compute(h)
        computeH((h & 1) ? As1 : As0, h);
    }

#pragma unroll
    for (int t = 0; t < 2; ++t)
#pragma unroll
        for (int c = 0; c < 4; ++c)
#pragma unroll
            for (int r = 0; r < 4; ++r) {
                int rr = row0 + wr * 32 + t * 16 + grp * 4 + r;
                int cc = col0 + wc * 64 + c * 16 + lm;
                out[(size_t)rr * S + cc] = (cc <= rr) ? accP[t][c][r] : NEGF;
            }
}

// ---------------------------------------------------------------------------
// Top-k via 4-round radix select (11-bit digits over unique 44-bit keys).
// ---------------------------------------------------------------------------
__device__ __forceinline__ unsigned mono32(float f)
{
    unsigned u = __float_as_uint(f);
    return (u & 0x80000000u) ? ~u : (u | 0x80000000u);
}

__global__ __launch_bounds__(256) void topk_select(
    const float* __restrict__ logits, float* __restrict__ out_idx)
{
    const int row = blockIdx.x;
    const int tid = threadIdx.x;
    const int valid = row + 1;
    float* orow = out_idx + (size_t)row * TOPK_N;

    if (valid <= TOPK_N) {
        for (int p = tid; p < TOPK_N; p += 256)
            orow[p] = (p < valid) ? (float)p : -1.0f;
        return;
    }

    __shared__ float vals[S];
    __shared__ unsigned hist[2048];
    __shared__ unsigned chunk[256];
    __shared__ unsigned long long sh_prefix;
    __shared__ int sh_rem;
    __shared__ unsigned sh_cnt;

    const float* lr = logits + (size_t)row * S;
    for (int j = tid; j < valid; j += 256) vals[j] = lr[j];
    if (tid == 0) { sh_prefix = 0ull; sh_rem = TOPK_N; sh_cnt = 0u; }
    __syncthreads();

    for (int rnd = 0; rnd < 4; ++rnd) {
        const int shift = 33 - 11 * rnd;
        for (int i = tid; i < 2048; i += 256) hist[i] = 0u;
        __syncthreads();
        const unsigned long long pref = sh_prefix;
        const int rem = sh_rem;
        const int hs = shift + 11;
        for (int j = tid; j < valid; j += 256) {
            unsigned long long key = (((unsigned long long)mono32(vals[j])) << 12)
                                   | (unsigned)(4095 - j);
            if ((key >> hs) == (pref >> hs))
                atomicAdd(&hist[(unsigned)(key >> shift) & 2047u], 1u);
        }
        __syncthreads();
        unsigned csum = 0;
#pragma unroll
        for (int d = 0; d < 8; ++d) csum += hist[tid * 8 + d];
        chunk[tid] = csum;
        __syncthreads();
        for (int off = 1; off < 256; off <<= 1) {
            unsigned v = (tid + off < 256) ? chunk[tid + off] : 0u;
            __syncthreads();
            chunk[tid] += v;
            __syncthreads();
        }
        unsigned A = (tid < 255) ? chunk[tid + 1] : 0u;
        for (int dd = 7; dd >= 0; --dd) {
            unsigned c = hist[tid * 8 + dd];
            if (c && A < (unsigned)rem && (unsigned)rem <= A + c) {
                sh_prefix = pref | ((unsigned long long)(tid * 8 + dd) << shift);
                sh_rem = rem - (int)A;
            }
            A += c;
        }
        __syncthreads();
    }

    const unsigned long long Kstar = sh_prefix;
    for (int j = tid; j < valid; j += 256) {
        unsigned long long key = (((unsigned long long)mono32(vals[j])) << 12)
                               | (unsigned)(4095 - j);
        if (key >= Kstar) {
            unsigned p = atomicAdd(&sh_cnt, 1u);
            orow[p] = (float)j;
        }
    }
}

// ---------------------------------------------------------------------------
extern "C" void kernel_launch(void* const* d_in, const int* in_sizes, int n_in,
                              void* d_out, int out_size, void* d_ws, size_t ws_size,
                              hipStream_t stream)
{
    const float* hidden    = (const float*)d_in[0];
    const float* q_lora    = (const float*)d_in[1];
    const int*   positions = (const int*)d_in[2];
    const float* Wq        = (const float*)d_in[3];
    const float* Wk        = (const float*)d_in[4];
    const float* k_gamma   = (const float*)d_in[5];
    const float* k_beta    = (const float*)d_in[6];
    const float* Wp        = (const float*)d_in[7];

    char* ws = (char*)d_ws;
    size_t off = 0;
    __hip_bfloat16* qb16 = (__hip_bfloat16*)(ws + off); off += (size_t)S * H * D * 2;
    __hip_bfloat16* qlb  = (__hip_bfloat16*)(ws + off); off += (size_t)S * QLR * 2;
    __hip_bfloat16* WqT  = (__hip_bfloat16*)(ws + off); off += (size_t)(H * D) * QLR * 2;
    __hip_bfloat16* hb   = (__hip_bfloat16*)(ws + off); off += (size_t)S * HID * 2;
    __hip_bfloat16* WkpT = (__hip_bfloat16*)(ws + off); off += (size_t)KW_N * HID * 2;
    float* kf32 = (float*)(ws + off); off += (size_t)S * D * 4;
    __hip_bfloat16* kb16 = (__hip_bfloat16*)(ws + off); off += (size_t)S * D * 2;
    float* wbuf = (float*)(ws + off); off += (size_t)S * H * 4;
    float* cosT = (float*)(ws + off); off += (size_t)S * 32 * 4;
    float* sinT = (float*)(ws + off); off += (size_t)S * 32 * 4;

    float* out_logits = (float*)d_out;
    float* out_idx = out_logits + (size_t)S * S;

    // 1) casts for the q GEMM
    cast_bf16_kernel<<<(S * QLR / 4 + 255) / 256, 256, 0, stream>>>(q_lora, qlb, S * QLR / 4);
    transpose_cast_kernel<<<dim3((H * D) / 32, QLR / 32), 256, 0, stream>>>(Wq, WqT);

    // 2) q = q_lora @ Wq  (bf16 MFMA, BK=64 dbuf)
    gemm_bf16_bt<<<dim3((H * D) / 128, S / 128), 256, 0, stream>>>(
        qlb, WqT, qb16, S, H * D, QLR);

    // 3) fused k/w projection, split-K=4 MFMA + f32 atomics
    cast_bf16_kernel<<<(S * HID / 4 + 255) / 256, 256, 0, stream>>>(hidden, hb, S * HID / 4);
    build_wkpT<<<(KW_N * HID + 255) / 256, 256, 0, stream>>>(Wk, Wp, WkpT);
    zero_f32<<<(S * D + 255) / 256, 256, 0, stream>>>(kf32, S * D);
    zero_f32<<<(S * H + 255) / 256, 256, 0, stream>>>(wbuf, S * H);
    kw_mfma<<<dim3(S / 64, 4), 256, 0, stream>>>(
        (const short*)hb, (const short*)WkpT, kf32, wbuf);

    // 4) RoPE trig table
    sincos_table_kernel<<<(S * 32) / 256, 256, 0, stream>>>(positions, cosT, sinT);

    // 5) k: LN + RoPE + FWHT -> bf16 ; q: RoPE + FWHT in place (bf16)
    post_wave<<<(S + 3) / 4, 256, 0, stream>>>(
        kf32, 0, kb16, cosT, sinT, k_gamma, k_beta, 1, 1, S);
    post_wave<<<(S * H + 3) / 4, 256, 0, stream>>>(
        qb16, 1, qb16, cosT, sinT, nullptr, nullptr, H, 0, S * H);

    // 6) logits (single-barrier pipelined head loop)
    logits_mfma<<<dim3(S / 128, S / 64), 256, 0, stream>>>(
        (const short*)qb16, (const short*)kb16, wbuf, out_logits);

    // 7) top-k indices (radix select, written as float)
    topk_select<<<S, 256, 0, stream>>>(out_logits, out_idx);
}